// Round 1
// baseline (963.102 us; speedup 1.0000x reference)
//
#include <hip/hip_runtime.h>

#define U_CNT 100000
#define I_CNT 50000
#define D_DIM 64
#define N_NODES 150000  // U + I

// One wave (64 lanes) per edge; lane = embedding dim.
// Gather ego[src], scale by val, atomicAdd into out[dst].
__global__ void lgcn_scatter(const int* __restrict__ src,
                             const int* __restrict__ dst,
                             const float* __restrict__ val,
                             const float* __restrict__ ego,
                             float* __restrict__ out,
                             int nE) {
    int gid  = blockIdx.x * blockDim.x + threadIdx.x;
    int e    = gid >> 6;          // wave index = edge index
    int lane = threadIdx.x & 63;  // dim index
    if (e >= nE) return;
    int   s = src[e];
    int   d = dst[e];
    float v = val[e];
    float x = ego[(size_t)s * D_DIM + lane] * v;
    atomicAdd(&out[(size_t)d * D_DIM + lane], x);
}

// acc += ego   (vectorized float4)
__global__ void lgcn_acc(const float4* __restrict__ ego,
                         float4* __restrict__ acc,
                         int n4) {
    int i = blockIdx.x * blockDim.x + threadIdx.x;
    if (i < n4) {
        float4 a = acc[i];
        float4 e = ego[i];
        a.x += e.x; a.y += e.y; a.z += e.z; a.w += e.w;
        acc[i] = a;
    }
}

// acc = (acc + ego) / 3   (final layer, fused scale)
__global__ void lgcn_acc_scale(const float4* __restrict__ ego,
                               float4* __restrict__ acc,
                               int n4) {
    const float s = 1.0f / 3.0f;
    int i = blockIdx.x * blockDim.x + threadIdx.x;
    if (i < n4) {
        float4 a = acc[i];
        float4 e = ego[i];
        a.x = (a.x + e.x) * s; a.y = (a.y + e.y) * s;
        a.z = (a.z + e.z) * s; a.w = (a.w + e.w) * s;
        acc[i] = a;
    }
}

extern "C" void kernel_launch(void* const* d_in, const int* in_sizes, int n_in,
                              void* d_out, int out_size, void* d_ws, size_t ws_size,
                              hipStream_t stream) {
    const float* user_emb  = (const float*)d_in[0];
    const float* item_emb  = (const float*)d_in[1];
    const int*   edge_src  = (const int*)d_in[2];
    const int*   edge_dst  = (const int*)d_in[3];
    const float* edge_vals = (const float*)d_in[4];
    const int    nE        = in_sizes[2];  // 2E

    float* out = (float*)d_out;
    const size_t nd = (size_t)N_NODES * D_DIM;  // 9.6M floats

    // ws layout: two ping-pong ego buffers
    float* ego_a = (float*)d_ws;
    float* ego_b = ego_a + nd;

    // ego_0 = concat(user_emb, item_emb); acc = 0
    hipMemcpyAsync(ego_a, user_emb, (size_t)U_CNT * D_DIM * sizeof(float),
                   hipMemcpyDeviceToDevice, stream);
    hipMemcpyAsync(ego_a + (size_t)U_CNT * D_DIM, item_emb,
                   (size_t)I_CNT * D_DIM * sizeof(float),
                   hipMemcpyDeviceToDevice, stream);
    hipMemsetAsync(out, 0, nd * sizeof(float), stream);

    const int block = 256;                       // 4 waves/block
    const int waves_per_block = block / 64;
    const int scatter_grid = (nE + waves_per_block - 1) / waves_per_block;
    const int n4 = (int)(nd / 4);
    const int acc_grid = (n4 + block - 1) / block;

    float* cur = ego_a;
    float* nxt = ego_b;
    for (int layer = 0; layer < 3; ++layer) {
        hipMemsetAsync(nxt, 0, nd * sizeof(float), stream);
        lgcn_scatter<<<scatter_grid, block, 0, stream>>>(
            edge_src, edge_dst, edge_vals, cur, nxt, nE);
        if (layer < 2) {
            lgcn_acc<<<acc_grid, block, 0, stream>>>(
                (const float4*)nxt, (float4*)out, n4);
        } else {
            lgcn_acc_scale<<<acc_grid, block, 0, stream>>>(
                (const float4*)nxt, (float4*)out, n4);
        }
        float* t = cur; cur = nxt; nxt = t;
    }
}

// Round 2
// 613.209 us; speedup vs baseline: 1.5706x; 1.5706x over previous
//
#include <hip/hip_runtime.h>

#define U_CNT 100000
#define I_CNT 50000
#define D_DIM 64
#define N_NODES 150000  // U + I
#define SCAN_BLK 256

// ---------- CSR build ----------

__global__ void deg_hist(const int* __restrict__ dst, int* __restrict__ deg, int nE) {
    int e = blockIdx.x * blockDim.x + threadIdx.x;
    if (e < nE) atomicAdd(&deg[dst[e]], 1);
}

// per-block sums of deg
__global__ void block_sums(const int* __restrict__ deg, int* __restrict__ blksum, int n) {
    __shared__ int sm[SCAN_BLK];
    int i = blockIdx.x * SCAN_BLK + threadIdx.x;
    sm[threadIdx.x] = (i < n) ? deg[i] : 0;
    __syncthreads();
    for (int off = SCAN_BLK / 2; off > 0; off >>= 1) {
        if (threadIdx.x < off) sm[threadIdx.x] += sm[threadIdx.x + off];
        __syncthreads();
    }
    if (threadIdx.x == 0) blksum[blockIdx.x] = sm[0];
}

// single-block exclusive scan of block sums (nb <= 1024); writes row_ptr[N]=total
__global__ void scan_blksums(const int* __restrict__ blksum, int* __restrict__ blkoff,
                             int* __restrict__ row_ptr, int nb) {
    __shared__ int sm[1024];
    int t = threadIdx.x;
    int v = (t < nb) ? blksum[t] : 0;
    sm[t] = v;
    __syncthreads();
    for (int off = 1; off < 1024; off <<= 1) {
        int x = (t >= off) ? sm[t - off] : 0;
        __syncthreads();
        sm[t] += x;
        __syncthreads();
    }
    if (t < nb) blkoff[t] = sm[t] - v;              // exclusive
    if (t == nb - 1) row_ptr[N_NODES] = sm[t];      // total = nE
}

// within-block exclusive scan + block offset -> row_ptr
__global__ void scan_within(const int* __restrict__ deg, const int* __restrict__ blkoff,
                            int* __restrict__ row_ptr, int n) {
    __shared__ int sm[SCAN_BLK];
    int i = blockIdx.x * SCAN_BLK + threadIdx.x;
    int t = threadIdx.x;
    int d = (i < n) ? deg[i] : 0;
    sm[t] = d;
    __syncthreads();
    for (int off = 1; off < SCAN_BLK; off <<= 1) {
        int x = (t >= off) ? sm[t - off] : 0;
        __syncthreads();
        sm[t] += x;
        __syncthreads();
    }
    if (i < n) row_ptr[i] = blkoff[blockIdx.x] + sm[t] - d;
}

__global__ void csr_fill(const int* __restrict__ src, const int* __restrict__ dst,
                         const float* __restrict__ val, int* __restrict__ wptr,
                         int* __restrict__ csr_src, float* __restrict__ csr_val, int nE) {
    int e = blockIdx.x * blockDim.x + threadIdx.x;
    if (e >= nE) return;
    int d = dst[e];
    int pos = atomicAdd(&wptr[d], 1);
    csr_src[pos] = src[e];
    csr_val[pos] = val[e];
}

// ---------- gather SpMM, one wave per node, lane = dim ----------
// MODE 0: ego_in is concat(user,item) read from the two input arrays;
//         writes ego_out and out = acc
// MODE 1: reads ego_in, writes ego_out, out += acc
// MODE 2: reads ego_in, out = (out + acc)/3, no ego_out
template <int MODE>
__global__ void lgcn_spmm(const int* __restrict__ row_ptr,
                          const int* __restrict__ csr_src,
                          const float* __restrict__ csr_val,
                          const float* __restrict__ ego_in,
                          const float* __restrict__ user_emb,
                          const float* __restrict__ item_emb,
                          float* __restrict__ ego_out,
                          float* __restrict__ out) {
    int node = (blockIdx.x * blockDim.x + threadIdx.x) >> 6;
    int lane = threadIdx.x & 63;
    if (node >= N_NODES) return;
    int beg = row_ptr[node];
    int end = row_ptr[node + 1];
    float acc = 0.0f;
    for (int j = beg; j < end; ++j) {
        int s = csr_src[j];
        float v = csr_val[j];
        float x;
        if (MODE == 0) {
            x = (s < U_CNT) ? user_emb[(size_t)s * D_DIM + lane]
                            : item_emb[(size_t)(s - U_CNT) * D_DIM + lane];
        } else {
            x = ego_in[(size_t)s * D_DIM + lane];
        }
        acc = fmaf(v, x, acc);
    }
    size_t o = (size_t)node * D_DIM + lane;
    if (MODE == 0) {
        ego_out[o] = acc;
        out[o] = acc;
    } else if (MODE == 1) {
        ego_out[o] = acc;
        out[o] += acc;
    } else {
        out[o] = (out[o] + acc) * (1.0f / 3.0f);
    }
}

extern "C" void kernel_launch(void* const* d_in, const int* in_sizes, int n_in,
                              void* d_out, int out_size, void* d_ws, size_t ws_size,
                              hipStream_t stream) {
    const float* user_emb  = (const float*)d_in[0];
    const float* item_emb  = (const float*)d_in[1];
    const int*   edge_src  = (const int*)d_in[2];
    const int*   edge_dst  = (const int*)d_in[3];
    const float* edge_vals = (const float*)d_in[4];
    const int    nE        = in_sizes[2];  // 2E = 1.2M

    float* out = (float*)d_out;
    const size_t nd = (size_t)N_NODES * D_DIM;  // 9.6M floats

    // ---- ws layout ----
    char* p = (char*)d_ws;
    float* ego_a   = (float*)p;  p += nd * sizeof(float);          // 38.4 MB
    float* ego_b   = (float*)p;  p += nd * sizeof(float);          // 38.4 MB
    int*   deg     = (int*)p;    p += (size_t)N_NODES * 4;
    int*   row_ptr = (int*)p;    p += (size_t)(N_NODES + 1) * 4;
    int*   wptr    = (int*)p;    p += (size_t)N_NODES * 4;
    int*   csr_src = (int*)p;    p += (size_t)nE * 4;              // 4.8 MB
    float* csr_val = (float*)p;  p += (size_t)nE * 4;              // 4.8 MB
    const int NB = (N_NODES + SCAN_BLK - 1) / SCAN_BLK;            // 586
    int* blksum = (int*)p;  p += (size_t)NB * 4;
    int* blkoff = (int*)p;  p += (size_t)NB * 4;

    const int block = 256;

    // ---- CSR build ----
    hipMemsetAsync(deg, 0, (size_t)N_NODES * 4, stream);
    deg_hist<<<(nE + block - 1) / block, block, 0, stream>>>(edge_dst, deg, nE);
    block_sums<<<NB, SCAN_BLK, 0, stream>>>(deg, blksum, N_NODES);
    scan_blksums<<<1, 1024, 0, stream>>>(blksum, blkoff, row_ptr, NB);
    scan_within<<<NB, SCAN_BLK, 0, stream>>>(deg, blkoff, row_ptr, N_NODES);
    hipMemcpyAsync(wptr, row_ptr, (size_t)N_NODES * 4, hipMemcpyDeviceToDevice, stream);
    csr_fill<<<(nE + block - 1) / block, block, 0, stream>>>(
        edge_src, edge_dst, edge_vals, wptr, csr_src, csr_val, nE);

    // ---- 3 SpMM layers (gather), acc fused ----
    const int waves_per_block = block / 64;
    const int spmm_grid = (N_NODES + waves_per_block - 1) / waves_per_block;

    lgcn_spmm<0><<<spmm_grid, block, 0, stream>>>(
        row_ptr, csr_src, csr_val, nullptr, user_emb, item_emb, ego_a, out);
    lgcn_spmm<1><<<spmm_grid, block, 0, stream>>>(
        row_ptr, csr_src, csr_val, ego_a, nullptr, nullptr, ego_b, out);
    lgcn_spmm<2><<<spmm_grid, block, 0, stream>>>(
        row_ptr, csr_src, csr_val, ego_b, nullptr, nullptr, nullptr, out);
}

// Round 3
// 327.278 us; speedup vs baseline: 2.9428x; 1.8737x over previous
//
#include <hip/hip_runtime.h>

#define U_CNT 100000
#define I_CNT 50000
#define D_DIM 64
#define N_NODES 150000  // U + I
#define SCAN_BLK 256

// ---------- CSR build ----------

// pass 1: degree histogram + per-edge rank (position within its dst bucket)
__global__ void deg_hist_rank(const int* __restrict__ dst, int* __restrict__ deg,
                              int* __restrict__ rank, int nE) {
    int e = blockIdx.x * blockDim.x + threadIdx.x;
    if (e < nE) rank[e] = atomicAdd(&deg[dst[e]], 1);
}

__global__ void block_sums(const int* __restrict__ deg, int* __restrict__ blksum, int n) {
    __shared__ int sm[SCAN_BLK];
    int i = blockIdx.x * SCAN_BLK + threadIdx.x;
    sm[threadIdx.x] = (i < n) ? deg[i] : 0;
    __syncthreads();
    for (int off = SCAN_BLK / 2; off > 0; off >>= 1) {
        if (threadIdx.x < off) sm[threadIdx.x] += sm[threadIdx.x + off];
        __syncthreads();
    }
    if (threadIdx.x == 0) blksum[blockIdx.x] = sm[0];
}

__global__ void scan_blksums(const int* __restrict__ blksum, int* __restrict__ blkoff,
                             int* __restrict__ row_ptr, int nb) {
    __shared__ int sm[1024];
    int t = threadIdx.x;
    int v = (t < nb) ? blksum[t] : 0;
    sm[t] = v;
    __syncthreads();
    for (int off = 1; off < 1024; off <<= 1) {
        int x = (t >= off) ? sm[t - off] : 0;
        __syncthreads();
        sm[t] += x;
        __syncthreads();
    }
    if (t < nb) blkoff[t] = sm[t] - v;              // exclusive
    if (t == nb - 1) row_ptr[N_NODES] = sm[t];      // total = nE
}

__global__ void scan_within(const int* __restrict__ deg, const int* __restrict__ blkoff,
                            int* __restrict__ row_ptr, int n) {
    __shared__ int sm[SCAN_BLK];
    int i = blockIdx.x * SCAN_BLK + threadIdx.x;
    int t = threadIdx.x;
    int d = (i < n) ? deg[i] : 0;
    sm[t] = d;
    __syncthreads();
    for (int off = 1; off < SCAN_BLK; off <<= 1) {
        int x = (t >= off) ? sm[t - off] : 0;
        __syncthreads();
        sm[t] += x;
        __syncthreads();
    }
    if (i < n) row_ptr[i] = blkoff[blockIdx.x] + sm[t] - d;
}

// pass 2: no atomics — pos = row_ptr[dst] + rank; pack (src, val) into int2
__global__ void csr_fill(const int* __restrict__ src, const int* __restrict__ dst,
                         const float* __restrict__ val, const int* __restrict__ row_ptr,
                         const int* __restrict__ rank, int2* __restrict__ csr, int nE) {
    int e = blockIdx.x * blockDim.x + threadIdx.x;
    if (e >= nE) return;
    int pos = row_ptr[dst[e]] + rank[e];
    csr[pos] = make_int2(src[e], __float_as_int(val[e]));
}

// ---------- gather SpMM: 16 lanes per node, float4 per lane ----------
// One wave = 4 independent nodes -> 4 dependent-chains in flight, dwordx4 gathers.
// MODE 0: gather from user_emb/item_emb; ego_out = acc; out = acc
// MODE 1: gather from ego_in; ego_out = acc; out += acc
// MODE 2: gather from ego_in; out = (out + acc)/3
template <int MODE>
__global__ void lgcn_spmm(const int* __restrict__ row_ptr,
                          const int2* __restrict__ csr,
                          const float4* __restrict__ ego_in,
                          const float4* __restrict__ user4,
                          const float4* __restrict__ item4,
                          float4* __restrict__ ego_out,
                          float4* __restrict__ out) {
    int node = (blockIdx.x * blockDim.x + threadIdx.x) >> 4;
    int l    = threadIdx.x & 15;           // float4 index within the 64-f32 row
    if (node >= N_NODES) return;
    int beg = row_ptr[node];
    int end = row_ptr[node + 1];
    float4 acc = make_float4(0.f, 0.f, 0.f, 0.f);

    int j = beg;
    int2 ecur = (j < end) ? csr[j] : make_int2(0, 0);
    while (j < end) {
        int jn = j + 1;
        int2 enext = (jn < end) ? csr[jn] : make_int2(0, 0);  // prefetch next entry
        float v = __int_as_float(ecur.y);
        float4 x;
        if (MODE == 0) {
            x = (ecur.x < U_CNT) ? user4[(size_t)ecur.x * 16 + l]
                                 : item4[(size_t)(ecur.x - U_CNT) * 16 + l];
        } else {
            x = ego_in[(size_t)ecur.x * 16 + l];
        }
        acc.x = fmaf(v, x.x, acc.x);
        acc.y = fmaf(v, x.y, acc.y);
        acc.z = fmaf(v, x.z, acc.z);
        acc.w = fmaf(v, x.w, acc.w);
        ecur = enext;
        j = jn;
    }

    size_t o = (size_t)node * 16 + l;
    if (MODE == 0) {
        ego_out[o] = acc;
        out[o] = acc;
    } else if (MODE == 1) {
        ego_out[o] = acc;
        float4 a = out[o];
        a.x += acc.x; a.y += acc.y; a.z += acc.z; a.w += acc.w;
        out[o] = a;
    } else {
        const float s = 1.0f / 3.0f;
        float4 a = out[o];
        a.x = (a.x + acc.x) * s; a.y = (a.y + acc.y) * s;
        a.z = (a.z + acc.z) * s; a.w = (a.w + acc.w) * s;
        out[o] = a;
    }
}

static inline size_t align_up(size_t x, size_t a) { return (x + a - 1) & ~(a - 1); }

extern "C" void kernel_launch(void* const* d_in, const int* in_sizes, int n_in,
                              void* d_out, int out_size, void* d_ws, size_t ws_size,
                              hipStream_t stream) {
    const float* user_emb  = (const float*)d_in[0];
    const float* item_emb  = (const float*)d_in[1];
    const int*   edge_src  = (const int*)d_in[2];
    const int*   edge_dst  = (const int*)d_in[3];
    const float* edge_vals = (const float*)d_in[4];
    const int    nE        = in_sizes[2];  // 2E = 1.2M

    float* out = (float*)d_out;
    const size_t nd = (size_t)N_NODES * D_DIM;  // 9.6M floats

    // ---- ws layout (persistent): csr entries, row_ptr, two ego buffers ----
    size_t off = 0;
    char* base = (char*)d_ws;
    int2* csr = (int2*)(base + off);      off = align_up(off + (size_t)nE * sizeof(int2), 256);
    int* row_ptr = (int*)(base + off);    off = align_up(off + (size_t)(N_NODES + 1) * 4, 256);
    float* ego_a = (float*)(base + off);  off = align_up(off + nd * sizeof(float), 256);
    float* ego_b = (float*)(base + off);  off = align_up(off + nd * sizeof(float), 256);

    // build-time scratch overlaid into ego_a's space (free until layer 1 writes it)
    const int NB = (N_NODES + SCAN_BLK - 1) / SCAN_BLK;  // 586
    int* rank   = (int*)ego_a;            // nE ints   = 4.8 MB
    int* deg    = rank + nE;              // N ints    = 0.6 MB
    int* blksum = deg + N_NODES;          // NB ints
    int* blkoff = blksum + NB;            // NB ints   (total 5.4 MB < 38.4 MB)

    const int block = 256;

    // ---- CSR build ----
    hipMemsetAsync(deg, 0, (size_t)N_NODES * 4, stream);
    deg_hist_rank<<<(nE + block - 1) / block, block, 0, stream>>>(edge_dst, deg, rank, nE);
    block_sums<<<NB, SCAN_BLK, 0, stream>>>(deg, blksum, N_NODES);
    scan_blksums<<<1, 1024, 0, stream>>>(blksum, blkoff, row_ptr, NB);
    scan_within<<<NB, SCAN_BLK, 0, stream>>>(deg, blkoff, row_ptr, N_NODES);
    csr_fill<<<(nE + block - 1) / block, block, 0, stream>>>(
        edge_src, edge_dst, edge_vals, row_ptr, rank, csr, nE);

    // ---- 3 SpMM layers (gather, float4, 16 lanes/node), acc fused ----
    const size_t threads = (size_t)N_NODES * 16;
    const int spmm_grid = (int)((threads + block - 1) / block);

    lgcn_spmm<0><<<spmm_grid, block, 0, stream>>>(
        row_ptr, csr, nullptr, (const float4*)user_emb, (const float4*)item_emb,
        (float4*)ego_a, (float4*)out);
    lgcn_spmm<1><<<spmm_grid, block, 0, stream>>>(
        row_ptr, csr, (const float4*)ego_a, nullptr, nullptr,
        (float4*)ego_b, (float4*)out);
    lgcn_spmm<2><<<spmm_grid, block, 0, stream>>>(
        row_ptr, csr, (const float4*)ego_b, nullptr, nullptr,
        nullptr, (float4*)out);
}

// Round 4
// 320.243 us; speedup vs baseline: 3.0074x; 1.0220x over previous
//
#include <hip/hip_runtime.h>

#define U_CNT 100000
#define I_CNT 50000
#define D_DIM 64
#define N_NODES 150000  // U + I
#define SCAN_BLK 256

// ---------- CSR build ----------

// pass 1: degree histogram + per-edge rank (position within its dst bucket)
__global__ void deg_hist_rank(const int* __restrict__ dst, int* __restrict__ deg,
                              int* __restrict__ rank, int nE) {
    int e = blockIdx.x * blockDim.x + threadIdx.x;
    if (e < nE) rank[e] = atomicAdd(&deg[dst[e]], 1);
}

__global__ void block_sums(const int* __restrict__ deg, int* __restrict__ blksum, int n) {
    __shared__ int sm[SCAN_BLK];
    int i = blockIdx.x * SCAN_BLK + threadIdx.x;
    sm[threadIdx.x] = (i < n) ? deg[i] : 0;
    __syncthreads();
    for (int off = SCAN_BLK / 2; off > 0; off >>= 1) {
        if (threadIdx.x < off) sm[threadIdx.x] += sm[threadIdx.x + off];
        __syncthreads();
    }
    if (threadIdx.x == 0) blksum[blockIdx.x] = sm[0];
}

__global__ void scan_blksums(const int* __restrict__ blksum, int* __restrict__ blkoff,
                             int* __restrict__ row_ptr, int nb) {
    __shared__ int sm[1024];
    int t = threadIdx.x;
    int v = (t < nb) ? blksum[t] : 0;
    sm[t] = v;
    __syncthreads();
    for (int off = 1; off < 1024; off <<= 1) {
        int x = (t >= off) ? sm[t - off] : 0;
        __syncthreads();
        sm[t] += x;
        __syncthreads();
    }
    if (t < nb) blkoff[t] = sm[t] - v;              // exclusive
    if (t == nb - 1) row_ptr[N_NODES] = sm[t];      // total = nE
}

__global__ void scan_within(const int* __restrict__ deg, const int* __restrict__ blkoff,
                            int* __restrict__ row_ptr, int n) {
    __shared__ int sm[SCAN_BLK];
    int i = blockIdx.x * SCAN_BLK + threadIdx.x;
    int t = threadIdx.x;
    int d = (i < n) ? deg[i] : 0;
    sm[t] = d;
    __syncthreads();
    for (int off = 1; off < SCAN_BLK; off <<= 1) {
        int x = (t >= off) ? sm[t - off] : 0;
        __syncthreads();
        sm[t] += x;
        __syncthreads();
    }
    if (i < n) row_ptr[i] = blkoff[blockIdx.x] + sm[t] - d;
}

// pass 2: no atomics — pos = row_ptr[dst] + rank; pack (src, val) into int2.
// Also zero the 4 padding entries past nE (prefetch overshoot safety).
__global__ void csr_fill(const int* __restrict__ src, const int* __restrict__ dst,
                         const float* __restrict__ val, const int* __restrict__ row_ptr,
                         const int* __restrict__ rank, int2* __restrict__ csr, int nE) {
    int e = blockIdx.x * blockDim.x + threadIdx.x;
    if (e < 4) csr[nE + e] = make_int2(0, 0);
    if (e >= nE) return;
    int pos = row_ptr[dst[e]] + rank[e];
    csr[pos] = make_int2(src[e], __float_as_int(val[e]));
}

// ---------- gather SpMM: 16 lanes per node, float4 per lane ----------
// Edge loop unrolled x4 with 4-entry prefetch: 4 independent dwordx4 gathers
// in flight per 16-lane group. csr[] is padded with 4 zero entries past nE so
// unconditional entry prefetch never reads OOB; gathers for over-read entries
// are never issued (guarded by loop bound / remainder checks).
// MODE 0: gather from user_emb/item_emb; ego_out = acc; out = acc
// MODE 1: gather from ego_in; ego_out = acc; out += acc
// MODE 2: gather from ego_in; out = (out + acc)/3
template <int MODE>
__global__ void lgcn_spmm(const int* __restrict__ row_ptr,
                          const int2* __restrict__ csr,
                          const float4* __restrict__ ego_in,
                          const float4* __restrict__ user4,
                          const float4* __restrict__ item4,
                          float4* __restrict__ ego_out,
                          float4* __restrict__ out) {
    int node = (blockIdx.x * blockDim.x + threadIdx.x) >> 4;
    int l    = threadIdx.x & 15;           // float4 index within the 64-f32 row
    if (node >= N_NODES) return;
    int beg = row_ptr[node];
    int end = row_ptr[node + 1];

    auto gather = [&](int s) -> float4 {
        if (MODE == 0) {
            return (s < U_CNT) ? user4[(size_t)s * 16 + l]
                               : item4[(size_t)(s - U_CNT) * 16 + l];
        } else {
            return ego_in[(size_t)s * 16 + l];
        }
    };

    // prime 4-entry pipeline (safe: csr padded to nE+4)
    int2 e0 = csr[beg], e1 = csr[beg + 1], e2 = csr[beg + 2], e3 = csr[beg + 3];
    float4 acc0 = make_float4(0.f, 0.f, 0.f, 0.f);
    float4 acc1 = make_float4(0.f, 0.f, 0.f, 0.f);
    int j = beg;
    while (j + 4 <= end) {
        // issue all 4 gathers back-to-back (independent, all in flight)
        float4 x0 = gather(e0.x);
        float4 x1 = gather(e1.x);
        float4 x2 = gather(e2.x);
        float4 x3 = gather(e3.x);
        // prefetch next 4 entries (may overshoot row end; values unused then)
        int2 n0 = csr[j + 4], n1 = csr[j + 5], n2 = csr[j + 6], n3 = csr[j + 7];
        float v0 = __int_as_float(e0.y), v1 = __int_as_float(e1.y);
        float v2 = __int_as_float(e2.y), v3 = __int_as_float(e3.y);
        acc0.x = fmaf(v0, x0.x, acc0.x); acc0.y = fmaf(v0, x0.y, acc0.y);
        acc0.z = fmaf(v0, x0.z, acc0.z); acc0.w = fmaf(v0, x0.w, acc0.w);
        acc1.x = fmaf(v1, x1.x, acc1.x); acc1.y = fmaf(v1, x1.y, acc1.y);
        acc1.z = fmaf(v1, x1.z, acc1.z); acc1.w = fmaf(v1, x1.w, acc1.w);
        acc0.x = fmaf(v2, x2.x, acc0.x); acc0.y = fmaf(v2, x2.y, acc0.y);
        acc0.z = fmaf(v2, x2.z, acc0.z); acc0.w = fmaf(v2, x2.w, acc0.w);
        acc1.x = fmaf(v3, x3.x, acc1.x); acc1.y = fmaf(v3, x3.y, acc1.y);
        acc1.z = fmaf(v3, x3.z, acc1.z); acc1.w = fmaf(v3, x3.w, acc1.w);
        e0 = n0; e1 = n1; e2 = n2; e3 = n3;
        j += 4;
    }
    int rem = end - j;  // 0..3, entries are e0..e2
    if (rem > 0) {
        float4 x = gather(e0.x);
        float v = __int_as_float(e0.y);
        acc0.x = fmaf(v, x.x, acc0.x); acc0.y = fmaf(v, x.y, acc0.y);
        acc0.z = fmaf(v, x.z, acc0.z); acc0.w = fmaf(v, x.w, acc0.w);
    }
    if (rem > 1) {
        float4 x = gather(e1.x);
        float v = __int_as_float(e1.y);
        acc1.x = fmaf(v, x.x, acc1.x); acc1.y = fmaf(v, x.y, acc1.y);
        acc1.z = fmaf(v, x.z, acc1.z); acc1.w = fmaf(v, x.w, acc1.w);
    }
    if (rem > 2) {
        float4 x = gather(e2.x);
        float v = __int_as_float(e2.y);
        acc0.x = fmaf(v, x.x, acc0.x); acc0.y = fmaf(v, x.y, acc0.y);
        acc0.z = fmaf(v, x.z, acc0.z); acc0.w = fmaf(v, x.w, acc0.w);
    }
    float4 acc = make_float4(acc0.x + acc1.x, acc0.y + acc1.y,
                             acc0.z + acc1.z, acc0.w + acc1.w);

    size_t o = (size_t)node * 16 + l;
    if (MODE == 0) {
        ego_out[o] = acc;
        out[o] = acc;
    } else if (MODE == 1) {
        ego_out[o] = acc;
        float4 a = out[o];
        a.x += acc.x; a.y += acc.y; a.z += acc.z; a.w += acc.w;
        out[o] = a;
    } else {
        const float s = 1.0f / 3.0f;
        float4 a = out[o];
        a.x = (a.x + acc.x) * s; a.y = (a.y + acc.y) * s;
        a.z = (a.z + acc.z) * s; a.w = (a.w + acc.w) * s;
        out[o] = a;
    }
}

static inline size_t align_up(size_t x, size_t a) { return (x + a - 1) & ~(a - 1); }

extern "C" void kernel_launch(void* const* d_in, const int* in_sizes, int n_in,
                              void* d_out, int out_size, void* d_ws, size_t ws_size,
                              hipStream_t stream) {
    const float* user_emb  = (const float*)d_in[0];
    const float* item_emb  = (const float*)d_in[1];
    const int*   edge_src  = (const int*)d_in[2];
    const int*   edge_dst  = (const int*)d_in[3];
    const float* edge_vals = (const float*)d_in[4];
    const int    nE        = in_sizes[2];  // 2E = 1.2M

    float* out = (float*)d_out;
    const size_t nd = (size_t)N_NODES * D_DIM;  // 9.6M floats

    // ---- ws layout (persistent): csr entries (+4 pad), row_ptr, two ego buffers ----
    size_t off = 0;
    char* base = (char*)d_ws;
    int2* csr = (int2*)(base + off);      off = align_up(off + (size_t)(nE + 4) * sizeof(int2), 256);
    int* row_ptr = (int*)(base + off);    off = align_up(off + (size_t)(N_NODES + 1) * 4, 256);
    float* ego_a = (float*)(base + off);  off = align_up(off + nd * sizeof(float), 256);
    float* ego_b = (float*)(base + off);  off = align_up(off + nd * sizeof(float), 256);

    // build-time scratch overlaid into ego_a's space (free until layer 1 writes it)
    const int NB = (N_NODES + SCAN_BLK - 1) / SCAN_BLK;  // 586
    int* rank   = (int*)ego_a;            // nE ints   = 4.8 MB
    int* deg    = rank + nE;              // N ints    = 0.6 MB
    int* blksum = deg + N_NODES;          // NB ints
    int* blkoff = blksum + NB;            // NB ints   (total 5.4 MB < 38.4 MB)

    const int block = 256;

    // ---- CSR build ----
    hipMemsetAsync(deg, 0, (size_t)N_NODES * 4, stream);
    deg_hist_rank<<<(nE + block - 1) / block, block, 0, stream>>>(edge_dst, deg, rank, nE);
    block_sums<<<NB, SCAN_BLK, 0, stream>>>(deg, blksum, N_NODES);
    scan_blksums<<<1, 1024, 0, stream>>>(blksum, blkoff, row_ptr, NB);
    scan_within<<<NB, SCAN_BLK, 0, stream>>>(deg, blkoff, row_ptr, N_NODES);
    csr_fill<<<(nE + block - 1) / block, block, 0, stream>>>(
        edge_src, edge_dst, edge_vals, row_ptr, rank, csr, nE);

    // ---- 3 SpMM layers (gather, float4, 16 lanes/node, x4 unroll), acc fused ----
    const size_t threads = (size_t)N_NODES * 16;
    const int spmm_grid = (int)((threads + block - 1) / block);

    lgcn_spmm<0><<<spmm_grid, block, 0, stream>>>(
        row_ptr, csr, nullptr, (const float4*)user_emb, (const float4*)item_emb,
        (float4*)ego_a, (float4*)out);
    lgcn_spmm<1><<<spmm_grid, block, 0, stream>>>(
        row_ptr, csr, (const float4*)ego_a, nullptr, nullptr,
        (float4*)ego_b, (float4*)out);
    lgcn_spmm<2><<<spmm_grid, block, 0, stream>>>(
        row_ptr, csr, (const float4*)ego_b, nullptr, nullptr,
        nullptr, (float4*)out);
}

// Round 5
// 267.383 us; speedup vs baseline: 3.6020x; 1.1977x over previous
//
#include <hip/hip_runtime.h>

#define U_CNT 100000
#define I_CNT 50000
#define D_DIM 64
#define N_NODES 150000  // U + I
#define SCAN_BLK 256

// ---------- bf16 helpers (manual: 2 bf16 packed per uint) ----------
__device__ __forceinline__ float blo(unsigned u) { return __uint_as_float(u << 16); }
__device__ __forceinline__ float bhi(unsigned u) { return __uint_as_float(u & 0xFFFF0000u); }
__device__ __forceinline__ unsigned f2b(float f) {  // fp32 -> bf16 bits, RNE
    unsigned b = __float_as_uint(f);
    return (b + 0x7FFFu + ((b >> 16) & 1u)) >> 16;
}
__device__ __forceinline__ unsigned pack2(float a, float b) {
    return f2b(a) | (f2b(b) << 16);
}

// ---------- CSR build (unchanged from R4) ----------

__global__ void deg_hist_rank(const int* __restrict__ dst, int* __restrict__ deg,
                              int* __restrict__ rank, int nE) {
    int e = blockIdx.x * blockDim.x + threadIdx.x;
    if (e < nE) rank[e] = atomicAdd(&deg[dst[e]], 1);
}

__global__ void block_sums(const int* __restrict__ deg, int* __restrict__ blksum, int n) {
    __shared__ int sm[SCAN_BLK];
    int i = blockIdx.x * SCAN_BLK + threadIdx.x;
    sm[threadIdx.x] = (i < n) ? deg[i] : 0;
    __syncthreads();
    for (int off = SCAN_BLK / 2; off > 0; off >>= 1) {
        if (threadIdx.x < off) sm[threadIdx.x] += sm[threadIdx.x + off];
        __syncthreads();
    }
    if (threadIdx.x == 0) blksum[blockIdx.x] = sm[0];
}

__global__ void scan_blksums(const int* __restrict__ blksum, int* __restrict__ blkoff,
                             int* __restrict__ row_ptr, int nb) {
    __shared__ int sm[1024];
    int t = threadIdx.x;
    int v = (t < nb) ? blksum[t] : 0;
    sm[t] = v;
    __syncthreads();
    for (int off = 1; off < 1024; off <<= 1) {
        int x = (t >= off) ? sm[t - off] : 0;
        __syncthreads();
        sm[t] += x;
        __syncthreads();
    }
    if (t < nb) blkoff[t] = sm[t] - v;              // exclusive
    if (t == nb - 1) row_ptr[N_NODES] = sm[t];      // total = nE
}

__global__ void scan_within(const int* __restrict__ deg, const int* __restrict__ blkoff,
                            int* __restrict__ row_ptr, int n) {
    __shared__ int sm[SCAN_BLK];
    int i = blockIdx.x * SCAN_BLK + threadIdx.x;
    int t = threadIdx.x;
    int d = (i < n) ? deg[i] : 0;
    sm[t] = d;
    __syncthreads();
    for (int off = 1; off < SCAN_BLK; off <<= 1) {
        int x = (t >= off) ? sm[t - off] : 0;
        __syncthreads();
        sm[t] += x;
        __syncthreads();
    }
    if (i < n) row_ptr[i] = blkoff[blockIdx.x] + sm[t] - d;
}

__global__ void csr_fill(const int* __restrict__ src, const int* __restrict__ dst,
                         const float* __restrict__ val, const int* __restrict__ row_ptr,
                         const int* __restrict__ rank, int2* __restrict__ csr, int nE) {
    int e = blockIdx.x * blockDim.x + threadIdx.x;
    if (e < 4) csr[nE + e] = make_int2(0, 0);
    if (e >= nE) return;
    int pos = row_ptr[dst[e]] + rank[e];
    csr[pos] = make_int2(src[e], __float_as_int(val[e]));
}

// ---------- input fp32 -> ego0 bf16 (streaming) ----------
__global__ void to_bf16(const float4* __restrict__ user4, const float4* __restrict__ item4,
                        uint2* __restrict__ ego0, int n4u, int n4) {
    int i = blockIdx.x * blockDim.x + threadIdx.x;
    if (i >= n4) return;
    float4 f = (i < n4u) ? user4[i] : item4[i - n4u];
    ego0[i] = make_uint2(pack2(f.x, f.y), pack2(f.z, f.w));
}

// ---------- gather SpMM: 8 lanes/node, 16 B (8 bf16) per lane ----------
__device__ __forceinline__ void fma8(float (&acc)[8], float v, uint4 g) {
    acc[0] = fmaf(v, blo(g.x), acc[0]); acc[1] = fmaf(v, bhi(g.x), acc[1]);
    acc[2] = fmaf(v, blo(g.y), acc[2]); acc[3] = fmaf(v, bhi(g.y), acc[3]);
    acc[4] = fmaf(v, blo(g.z), acc[4]); acc[5] = fmaf(v, bhi(g.z), acc[5]);
    acc[6] = fmaf(v, blo(g.w), acc[6]); acc[7] = fmaf(v, bhi(g.w), acc[7]);
}

// FINAL=0: gather ego_in, store bf16 ego_out (no out traffic)
// FINAL=1: gather ego_in (=e2 buffer), then out = (egoA + egoB + acc)/3 in fp32
template <int FINAL>
__global__ void lgcn_spmm(const int* __restrict__ row_ptr,
                          const int2* __restrict__ csr,
                          const uint4* __restrict__ ego_in,
                          uint4* __restrict__ ego_out,
                          const uint4* __restrict__ egoA,
                          const uint4* __restrict__ egoB,
                          float4* __restrict__ out) {
    int node = (blockIdx.x * blockDim.x + threadIdx.x) >> 3;
    int l    = threadIdx.x & 7;            // 16 B chunk within the 128 B bf16 row
    if (node >= N_NODES) return;
    int beg = row_ptr[node];
    int end = row_ptr[node + 1];

    float a0[8] = {0, 0, 0, 0, 0, 0, 0, 0};
    float a1[8] = {0, 0, 0, 0, 0, 0, 0, 0};

    // prime 4-entry pipeline (csr padded to nE+4)
    int2 e0 = csr[beg], e1 = csr[beg + 1], e2 = csr[beg + 2], e3 = csr[beg + 3];
    int j = beg;
    while (j + 4 <= end) {
        uint4 x0 = ego_in[(size_t)e0.x * 8 + l];
        uint4 x1 = ego_in[(size_t)e1.x * 8 + l];
        uint4 x2 = ego_in[(size_t)e2.x * 8 + l];
        uint4 x3 = ego_in[(size_t)e3.x * 8 + l];
        int2 n0 = csr[j + 4], n1 = csr[j + 5], n2 = csr[j + 6], n3 = csr[j + 7];
        fma8(a0, __int_as_float(e0.y), x0);
        fma8(a1, __int_as_float(e1.y), x1);
        fma8(a0, __int_as_float(e2.y), x2);
        fma8(a1, __int_as_float(e3.y), x3);
        e0 = n0; e1 = n1; e2 = n2; e3 = n3;
        j += 4;
    }
    int rem = end - j;  // 0..3
    if (rem > 0) fma8(a0, __int_as_float(e0.y), ego_in[(size_t)e0.x * 8 + l]);
    if (rem > 1) fma8(a1, __int_as_float(e1.y), ego_in[(size_t)e1.x * 8 + l]);
    if (rem > 2) fma8(a0, __int_as_float(e2.y), ego_in[(size_t)e2.x * 8 + l]);

    float acc[8];
#pragma unroll
    for (int k = 0; k < 8; ++k) acc[k] = a0[k] + a1[k];

    if (!FINAL) {
        uint4 r;
        r.x = pack2(acc[0], acc[1]); r.y = pack2(acc[2], acc[3]);
        r.z = pack2(acc[4], acc[5]); r.w = pack2(acc[6], acc[7]);
        ego_out[(size_t)node * 8 + l] = r;
    } else {
        uint4 a = egoA[(size_t)node * 8 + l];
        uint4 b = egoB[(size_t)node * 8 + l];
        const float s = 1.0f / 3.0f;
        float4 o0, o1;
        o0.x = (blo(a.x) + blo(b.x) + acc[0]) * s;
        o0.y = (bhi(a.x) + bhi(b.x) + acc[1]) * s;
        o0.z = (blo(a.y) + blo(b.y) + acc[2]) * s;
        o0.w = (bhi(a.y) + bhi(b.y) + acc[3]) * s;
        o1.x = (blo(a.z) + blo(b.z) + acc[4]) * s;
        o1.y = (bhi(a.z) + bhi(b.z) + acc[5]) * s;
        o1.z = (blo(a.w) + blo(b.w) + acc[6]) * s;
        o1.w = (bhi(a.w) + bhi(b.w) + acc[7]) * s;
        size_t ob = (size_t)node * 16 + 2 * l;   // float4 index into out
        out[ob]     = o0;
        out[ob + 1] = o1;
    }
}

static inline size_t align_up(size_t x, size_t a) { return (x + a - 1) & ~(a - 1); }

extern "C" void kernel_launch(void* const* d_in, const int* in_sizes, int n_in,
                              void* d_out, int out_size, void* d_ws, size_t ws_size,
                              hipStream_t stream) {
    const float* user_emb  = (const float*)d_in[0];
    const float* item_emb  = (const float*)d_in[1];
    const int*   edge_src  = (const int*)d_in[2];
    const int*   edge_dst  = (const int*)d_in[3];
    const float* edge_vals = (const float*)d_in[4];
    const int    nE        = in_sizes[2];  // 2E = 1.2M

    float* out = (float*)d_out;
    const size_t nd = (size_t)N_NODES * D_DIM;   // 9.6M floats
    const size_t row_u4 = 8;                     // uint4 per bf16 row

    // ---- ws layout: csr (+4 pad), row_ptr, three bf16 ego buffers ----
    size_t off = 0;
    char* base = (char*)d_ws;
    int2* csr = (int2*)(base + off);      off = align_up(off + (size_t)(nE + 4) * sizeof(int2), 256);
    int* row_ptr = (int*)(base + off);    off = align_up(off + (size_t)(N_NODES + 1) * 4, 256);
    uint4* ego0 = (uint4*)(base + off);   off = align_up(off + (size_t)N_NODES * row_u4 * 16, 256);
    uint4* ego_a = (uint4*)(base + off);  off = align_up(off + (size_t)N_NODES * row_u4 * 16, 256);
    uint4* ego_b = (uint4*)(base + off);  off = align_up(off + (size_t)N_NODES * row_u4 * 16, 256);

    // build-time scratch overlaid into ego_a's region (free until layer-1 SpMM writes it)
    const int NB = (N_NODES + SCAN_BLK - 1) / SCAN_BLK;  // 586
    int* rank   = (int*)ego_a;            // nE ints = 4.8 MB (< 19.2 MB region)
    int* deg    = rank + nE;
    int* blksum = deg + N_NODES;
    int* blkoff = blksum + NB;

    const int block = 256;

    // ---- CSR build ----
    hipMemsetAsync(deg, 0, (size_t)N_NODES * 4, stream);
    deg_hist_rank<<<(nE + block - 1) / block, block, 0, stream>>>(edge_dst, deg, rank, nE);
    block_sums<<<NB, SCAN_BLK, 0, stream>>>(deg, blksum, N_NODES);
    scan_blksums<<<1, 1024, 0, stream>>>(blksum, blkoff, row_ptr, NB);
    scan_within<<<NB, SCAN_BLK, 0, stream>>>(deg, blkoff, row_ptr, N_NODES);
    csr_fill<<<(nE + block - 1) / block, block, 0, stream>>>(
        edge_src, edge_dst, edge_vals, row_ptr, rank, csr, nE);

    // ---- inputs -> bf16 ego0 ----
    const int n4  = (int)(nd / 4);                 // 2.4M float4s
    const int n4u = U_CNT * D_DIM / 4;             // 1.6M
    to_bf16<<<(n4 + block - 1) / block, block, 0, stream>>>(
        (const float4*)user_emb, (const float4*)item_emb, (uint2*)ego0, n4u, n4);

    // ---- 3 SpMM layers (bf16 gather, 8 lanes/node, x4 unroll) ----
    const size_t threads = (size_t)N_NODES * 8;
    const int spmm_grid = (int)((threads + block - 1) / block);

    lgcn_spmm<0><<<spmm_grid, block, 0, stream>>>(
        row_ptr, csr, ego0, ego_a, nullptr, nullptr, nullptr);
    lgcn_spmm<0><<<spmm_grid, block, 0, stream>>>(
        row_ptr, csr, ego_a, ego_b, nullptr, nullptr, nullptr);
    lgcn_spmm<1><<<spmm_grid, block, 0, stream>>>(
        row_ptr, csr, ego_b, nullptr, ego_a, ego_b, (float4*)out);
}

// Round 6
// 235.885 us; speedup vs baseline: 4.0829x; 1.1335x over previous
//
#include <hip/hip_runtime.h>

#define U_CNT 100000
#define I_CNT 50000
#define D_DIM 64
#define N_NODES 150000            // U + I
#define CHUNK 2048                // edges per block in passes A/B
#define NBKT 586                  // ceil(N_NODES/256) coarse buckets (256 nodes each)
#define SCAN_BLK 512
#define CCAP 3584                 // LDS edge cache per bucket (max bucket ~3.4K)

// ---------- bf16 helpers ----------
__device__ __forceinline__ float blo(unsigned u) { return __uint_as_float(u << 16); }
__device__ __forceinline__ float bhi(unsigned u) { return __uint_as_float(u & 0xFFFF0000u); }
__device__ __forceinline__ unsigned f2b(float f) {  // fp32 -> bf16 bits, RNE
    unsigned b = __float_as_uint(f);
    return (b + 0x7FFFu + ((b >> 16) & 1u)) >> 16;
}
__device__ __forceinline__ unsigned pack2(float a, float b) {
    return f2b(a) | (f2b(b) << 16);
}

// ---------- Pass A: coarse LDS histogram (+ fused fp32->bf16 convert) ----------
// H layout bucket-major: H[bucket * NB_B + block]
__global__ void bucket_hist(const int* __restrict__ dst, int* __restrict__ H,
                            int NB_B, int nE,
                            const float4* __restrict__ user4,
                            const float4* __restrict__ item4,
                            uint2* __restrict__ ego0, int n4u, int n4) {
    __shared__ int h[NBKT];
    for (int i = threadIdx.x; i < NBKT; i += blockDim.x) h[i] = 0;
    __syncthreads();
    int b = blockIdx.x;
    int beg = b * CHUNK, end = min(nE, beg + CHUNK);
    for (int e = beg + (int)threadIdx.x; e < end; e += blockDim.x)
        atomicAdd(&h[dst[e] >> 8], 1);
    __syncthreads();
    for (int i = threadIdx.x; i < NBKT; i += blockDim.x) H[i * NB_B + b] = h[i];
    // fused streaming convert (independent work; this kernel is light)
    int gsz = gridDim.x * blockDim.x;
    for (int i = blockIdx.x * blockDim.x + threadIdx.x; i < n4; i += gsz) {
        float4 f = (i < n4u) ? user4[i] : item4[i - n4u];
        ego0[i] = make_uint2(pack2(f.x, f.y), pack2(f.z, f.w));
    }
}

// ---------- exclusive scan over H (nH = NBKT * NB_B ~= 343K) ----------
__global__ void block_sums(const int* __restrict__ in, int* __restrict__ blksum, int n) {
    __shared__ int sm[SCAN_BLK];
    int i = blockIdx.x * SCAN_BLK + threadIdx.x;
    sm[threadIdx.x] = (i < n) ? in[i] : 0;
    __syncthreads();
    for (int off = SCAN_BLK / 2; off > 0; off >>= 1) {
        if (threadIdx.x < off) sm[threadIdx.x] += sm[threadIdx.x + off];
        __syncthreads();
    }
    if (threadIdx.x == 0) blksum[blockIdx.x] = sm[0];
}

__global__ void scan_blksums(const int* __restrict__ blksum, int* __restrict__ blkoff, int nb) {
    __shared__ int sm[1024];
    int t = threadIdx.x;
    int v = (t < nb) ? blksum[t] : 0;
    sm[t] = v;
    __syncthreads();
    for (int off = 1; off < 1024; off <<= 1) {
        int x = (t >= off) ? sm[t - off] : 0;
        __syncthreads();
        sm[t] += x;
        __syncthreads();
    }
    if (t < nb) blkoff[t] = sm[t] - v;  // exclusive
}

// in-place: H[i] -> exclusive prefix
__global__ void scan_within(int* __restrict__ H, const int* __restrict__ blkoff, int n) {
    __shared__ int sm[SCAN_BLK];
    int i = blockIdx.x * SCAN_BLK + threadIdx.x;
    int t = threadIdx.x;
    int d = (i < n) ? H[i] : 0;
    sm[t] = d;
    __syncthreads();
    for (int off = 1; off < SCAN_BLK; off <<= 1) {
        int x = (t >= off) ? sm[t - off] : 0;
        __syncthreads();
        sm[t] += x;
        __syncthreads();
    }
    if (i < n) H[i] = blkoff[blockIdx.x] + sm[t] - d;
}

// ---------- Pass B: scatter edges into coarse buckets (LDS cursors, no global atomics) ----------
// record: x = src (18b) | finebin (8b) << 18 ; y = val bits
__global__ void bucket_scatter(const int* __restrict__ src, const int* __restrict__ dst,
                               const float* __restrict__ val, const int* __restrict__ Hs,
                               uint2* __restrict__ tmp, int NB_B, int nE) {
    __shared__ int cur[NBKT];
    int b = blockIdx.x;
    for (int i = threadIdx.x; i < NBKT; i += blockDim.x) cur[i] = Hs[i * NB_B + b];
    __syncthreads();
    int beg = b * CHUNK, end = min(nE, beg + CHUNK);
    for (int e = beg + (int)threadIdx.x; e < end; e += blockDim.x) {
        int d = dst[e];
        int pos = atomicAdd(&cur[d >> 8], 1);
        tmp[pos] = make_uint2((unsigned)src[e] | ((unsigned)(d & 255) << 18),
                              __float_as_uint(val[e]));
    }
}

// ---------- Pass C: per-bucket fine sort -> csr + row_ptr ----------
__global__ void bucket_build(const int* __restrict__ Hs, const uint2* __restrict__ tmp,
                             int2* __restrict__ csr, int* __restrict__ row_ptr,
                             int NB_B, int nE) {
    __shared__ int hist[256];
    __shared__ int scanbuf[256];
    __shared__ int cur[256];
    __shared__ uint2 cache[CCAP];
    int bkt  = blockIdx.x;
    int base = Hs[(size_t)bkt * NB_B];
    int endp = (bkt + 1 < NBKT) ? Hs[(size_t)(bkt + 1) * NB_B] : nE;
    int size = endp - base;
    int nbins = min(256, N_NODES - bkt * 256);
    int t = threadIdx.x;

    hist[t] = 0;
    __syncthreads();
    bool cached = (size <= CCAP);
    for (int k = t; k < size; k += blockDim.x) {
        uint2 r = tmp[base + k];
        if (cached) cache[k] = r;
        atomicAdd(&hist[(r.x >> 18) & 255], 1);
    }
    __syncthreads();
    // inclusive scan (Hillis-Steele) -> exclusive per-thread
    int v = hist[t];
    scanbuf[t] = v;
    __syncthreads();
    for (int off = 1; off < 256; off <<= 1) {
        int x = (t >= off) ? scanbuf[t - off] : 0;
        __syncthreads();
        scanbuf[t] += x;
        __syncthreads();
    }
    int ex = scanbuf[t] - v;
    if (t < nbins) row_ptr[bkt * 256 + t] = base + ex;
    cur[t] = ex;
    __syncthreads();
    if (bkt == NBKT - 1) {
        if (t == 0) row_ptr[N_NODES] = nE;
        if (t < 4)  csr[nE + t] = make_int2(0, 0);  // spmm prefetch pad
    }
    for (int k = t; k < size; k += blockDim.x) {
        uint2 r = cached ? cache[k] : tmp[base + k];
        int f = (r.x >> 18) & 255;
        int p = atomicAdd(&cur[f], 1);
        csr[base + p] = make_int2((int)(r.x & 0x3FFFFu), (int)r.y);
    }
}

// ---------- gather SpMM: 8 lanes/node, 16 B (8 bf16) per lane (unchanged R5) ----------
__device__ __forceinline__ void fma8(float (&acc)[8], float v, uint4 g) {
    acc[0] = fmaf(v, blo(g.x), acc[0]); acc[1] = fmaf(v, bhi(g.x), acc[1]);
    acc[2] = fmaf(v, blo(g.y), acc[2]); acc[3] = fmaf(v, bhi(g.y), acc[3]);
    acc[4] = fmaf(v, blo(g.z), acc[4]); acc[5] = fmaf(v, bhi(g.z), acc[5]);
    acc[6] = fmaf(v, blo(g.w), acc[6]); acc[7] = fmaf(v, bhi(g.w), acc[7]);
}

template <int FINAL>
__global__ void lgcn_spmm(const int* __restrict__ row_ptr,
                          const int2* __restrict__ csr,
                          const uint4* __restrict__ ego_in,
                          uint4* __restrict__ ego_out,
                          const uint4* __restrict__ egoA,
                          const uint4* __restrict__ egoB,
                          float4* __restrict__ out) {
    int node = (blockIdx.x * blockDim.x + threadIdx.x) >> 3;
    int l    = threadIdx.x & 7;
    if (node >= N_NODES) return;
    int beg = row_ptr[node];
    int end = row_ptr[node + 1];

    float a0[8] = {0, 0, 0, 0, 0, 0, 0, 0};
    float a1[8] = {0, 0, 0, 0, 0, 0, 0, 0};

    int2 e0 = csr[beg], e1 = csr[beg + 1], e2 = csr[beg + 2], e3 = csr[beg + 3];
    int j = beg;
    while (j + 4 <= end) {
        uint4 x0 = ego_in[(size_t)e0.x * 8 + l];
        uint4 x1 = ego_in[(size_t)e1.x * 8 + l];
        uint4 x2 = ego_in[(size_t)e2.x * 8 + l];
        uint4 x3 = ego_in[(size_t)e3.x * 8 + l];
        int2 n0 = csr[j + 4], n1 = csr[j + 5], n2 = csr[j + 6], n3 = csr[j + 7];
        fma8(a0, __int_as_float(e0.y), x0);
        fma8(a1, __int_as_float(e1.y), x1);
        fma8(a0, __int_as_float(e2.y), x2);
        fma8(a1, __int_as_float(e3.y), x3);
        e0 = n0; e1 = n1; e2 = n2; e3 = n3;
        j += 4;
    }
    int rem = end - j;  // 0..3
    if (rem > 0) fma8(a0, __int_as_float(e0.y), ego_in[(size_t)e0.x * 8 + l]);
    if (rem > 1) fma8(a1, __int_as_float(e1.y), ego_in[(size_t)e1.x * 8 + l]);
    if (rem > 2) fma8(a0, __int_as_float(e2.y), ego_in[(size_t)e2.x * 8 + l]);

    float acc[8];
#pragma unroll
    for (int k = 0; k < 8; ++k) acc[k] = a0[k] + a1[k];

    if (!FINAL) {
        uint4 r;
        r.x = pack2(acc[0], acc[1]); r.y = pack2(acc[2], acc[3]);
        r.z = pack2(acc[4], acc[5]); r.w = pack2(acc[6], acc[7]);
        ego_out[(size_t)node * 8 + l] = r;
    } else {
        uint4 a = egoA[(size_t)node * 8 + l];
        uint4 b = egoB[(size_t)node * 8 + l];
        const float s = 1.0f / 3.0f;
        float4 o0, o1;
        o0.x = (blo(a.x) + blo(b.x) + acc[0]) * s;
        o0.y = (bhi(a.x) + bhi(b.x) + acc[1]) * s;
        o0.z = (blo(a.y) + blo(b.y) + acc[2]) * s;
        o0.w = (bhi(a.y) + bhi(b.y) + acc[3]) * s;
        o1.x = (blo(a.z) + blo(b.z) + acc[4]) * s;
        o1.y = (bhi(a.z) + bhi(b.z) + acc[5]) * s;
        o1.z = (blo(a.w) + blo(b.w) + acc[6]) * s;
        o1.w = (bhi(a.w) + bhi(b.w) + acc[7]) * s;
        size_t ob = (size_t)node * 16 + 2 * l;
        out[ob]     = o0;
        out[ob + 1] = o1;
    }
}

static inline size_t align_up(size_t x, size_t a) { return (x + a - 1) & ~(a - 1); }

extern "C" void kernel_launch(void* const* d_in, const int* in_sizes, int n_in,
                              void* d_out, int out_size, void* d_ws, size_t ws_size,
                              hipStream_t stream) {
    const float* user_emb  = (const float*)d_in[0];
    const float* item_emb  = (const float*)d_in[1];
    const int*   edge_src  = (const int*)d_in[2];
    const int*   edge_dst  = (const int*)d_in[3];
    const float* edge_vals = (const float*)d_in[4];
    const int    nE        = in_sizes[2];  // 2E = 1.2M

    float* out = (float*)d_out;
    const size_t nd = (size_t)N_NODES * D_DIM;

    const int NB_B = (nE + CHUNK - 1) / CHUNK;           // 586
    const int nH   = NBKT * NB_B;                        // ~343K
    const int NBs  = (nH + SCAN_BLK - 1) / SCAN_BLK;     // 671 (<=1024)

    // ---- ws layout ----
    size_t off = 0;
    char* base = (char*)d_ws;
    int2*  csr     = (int2*)(base + off);  off = align_up(off + (size_t)(nE + 4) * sizeof(int2), 256);
    int*   row_ptr = (int*)(base + off);   off = align_up(off + (size_t)(N_NODES + 1) * 4, 256);
    uint2* tmp     = (uint2*)(base + off); off = align_up(off + (size_t)nE * sizeof(uint2), 256);
    int*   H       = (int*)(base + off);   off = align_up(off + (size_t)nH * 4, 256);
    int*   blksum  = (int*)(base + off);   off = align_up(off + (size_t)NBs * 4, 256);
    int*   blkoff  = (int*)(base + off);   off = align_up(off + (size_t)NBs * 4, 256);
    uint4* ego0    = (uint4*)(base + off); off = align_up(off + (size_t)N_NODES * 128, 256);
    uint4* ego_a   = (uint4*)(base + off); off = align_up(off + (size_t)N_NODES * 128, 256);
    uint4* ego_b   = (uint4*)(base + off); off = align_up(off + (size_t)N_NODES * 128, 256);

    const int block = 256;
    const int n4  = (int)(nd / 4);
    const int n4u = U_CNT * D_DIM / 4;

    // ---- atomic-free CSR build ----
    bucket_hist<<<NB_B, block, 0, stream>>>(edge_dst, H, NB_B, nE,
        (const float4*)user_emb, (const float4*)item_emb, (uint2*)ego0, n4u, n4);
    block_sums<<<NBs, SCAN_BLK, 0, stream>>>(H, blksum, nH);
    scan_blksums<<<1, 1024, 0, stream>>>(blksum, blkoff, NBs);
    scan_within<<<NBs, SCAN_BLK, 0, stream>>>(H, blkoff, nH);
    bucket_scatter<<<NB_B, block, 0, stream>>>(edge_src, edge_dst, edge_vals, H, tmp, NB_B, nE);
    bucket_build<<<NBKT, block, 0, stream>>>(H, tmp, csr, row_ptr, NB_B, nE);

    // ---- 3 SpMM layers (bf16 gather, 8 lanes/node, x4 unroll) ----
    const size_t threads = (size_t)N_NODES * 8;
    const int spmm_grid = (int)((threads + block - 1) / block);

    lgcn_spmm<0><<<spmm_grid, block, 0, stream>>>(
        row_ptr, csr, ego0, ego_a, nullptr, nullptr, nullptr);
    lgcn_spmm<0><<<spmm_grid, block, 0, stream>>>(
        row_ptr, csr, ego_a, ego_b, nullptr, nullptr, nullptr);
    lgcn_spmm<1><<<spmm_grid, block, 0, stream>>>(
        row_ptr, csr, ego_b, nullptr, ego_a, ego_b, (float4*)out);
}